// Round 2
// baseline (746.341 us; speedup 1.0000x reference)
//
#include <hip/hip_runtime.h>
#include <hip/hip_bf16.h>

#define BATCH 1024
#define F_IN 256
#define N_D 64
#define N_A 64
#define VBS 128
#define N_STEPS 3
#define FO 128
#define D_CAT 512
#define AD 256
#define GAMMA_C 1.3f
#define BN_EPS_C 1e-5f
#define SQRT_HALF_C 0.70710678118654752440f

// ---- input loader: f32 or bf16 decided at runtime by detector flag --------
__device__ __forceinline__ float ldin(const void* p, size_t i, int isbf){
  if (isbf) return __bfloat162float(((const __hip_bfloat16*)p)[i]);
  return ((const float*)p)[i];
}

// ---- LDS-tree block reductions (256 threads). OP: 0=sum 1=max 2=min -------
template<int OP>
__device__ __forceinline__ float block_red(float v, float* sb){
  int t = threadIdx.x;
  sb[t] = v; __syncthreads();
#pragma unroll
  for (int s = 128; s > 0; s >>= 1){
    if (t < s){
      float a = sb[t], b = sb[t + s];
      sb[t] = (OP == 0) ? (a + b) : (OP == 1 ? fmaxf(a, b) : fminf(a, b));
    }
    __syncthreads();
  }
  float r = sb[0];
  __syncthreads();
  return r;
}

// ---- dtype detector: even-indexed uint16s of an f32 N(0,1) buffer are
// uniform-random mantissa bits; of a bf16 buffer they are bf16 values whose
// exponent sits in a narrow band. ------------------------------------------
__global__ void detect_k(const unsigned short* __restrict__ u, float* __restrict__ flag){
  __shared__ int cnt;
  if (threadIdx.x == 0) cnt = 0;
  __syncthreads();
  int c = 0;
  for (int j = 0; j < 16; ++j){
    unsigned short v = u[(size_t)(threadIdx.x * 16 + j) * 2];
    int e = (v >> 7) & 0xFF;
    if (e >= 118 && e <= 134) c++;
  }
  atomicAdd(&cnt, c);
  __syncthreads();
  if (threadIdx.x == 0) flag[0] = (cnt > 2048) ? 1.0f : 0.0f;  // of 4096 samples
}

// ---- init: prior = 1 -------------------------------------------------------
__global__ void init_k(float* __restrict__ prior){
  prior[blockIdx.x * 256 + threadIdx.x] = 1.0f;
}

// ---- full-batch BN stats (one block per feature) ---------------------------
__global__ void bnstats_k(const void* __restrict__ x, float* __restrict__ mean,
                          float* __restrict__ istd, const float* __restrict__ flg){
  __shared__ float sb[256];
  const int isbf = flg[0] != 0.0f;
  int f = blockIdx.x, t = threadIdx.x;
  float s = 0.f, ss = 0.f;
  for (int r = t; r < BATCH; r += 256){
    float v = ldin(x, (size_t)r * F_IN + f, isbf);
    s += v; ss += v * v;
  }
  s  = block_red<0>(s, sb);
  ss = block_red<0>(ss, sb);
  if (t == 0){
    float m = s * (1.f / BATCH);
    mean[f] = m;
    istd[f] = rsqrtf(ss * (1.f / BATCH) - m * m + BN_EPS_C);
  }
}

__global__ void xn_k(const void* __restrict__ x, const float* __restrict__ mean,
                     const float* __restrict__ istd, const void* __restrict__ bw,
                     const void* __restrict__ bb, float* __restrict__ xn,
                     const float* __restrict__ flg){
  const int isbf = flg[0] != 0.0f;
  int idx = blockIdx.x * 256 + threadIdx.x;   // 262144 total
  int f = idx & (F_IN - 1);
  xn[idx] = (ldin(x, idx, isbf) - mean[f]) * istd[f] * ldin(bw, f, isbf) + ldin(bb, f, isbf);
}

// ---- GEMM: C(MxN) = A(MxK) @ W ; W is (N,K) row-major if BT else (K,N).
// A = virtual concat [A1 (f32 ws) | A2 (input)] split at `split` columns.
// W is an input; woff is its element offset (dtype-safe slicing). -----------
template<bool BT, bool MUL>
__global__ __launch_bounds__(256)
void gemm_k(const float* __restrict__ A1, const void* __restrict__ A2, int split,
            const void* __restrict__ W, size_t woff, const float* __restrict__ mulv,
            float* __restrict__ C, int M, int N, int K, const float* __restrict__ flg){
  __shared__ float As[32][17];
  __shared__ float Ws[16][33];
  const int isbf = flg[0] != 0.0f;
  const int n0 = blockIdx.x * 32, m0 = blockIdx.y * 32;
  const int t = threadIdx.x;
  const int tx = t & 15, ty = t >> 4;
  float acc00 = 0.f, acc01 = 0.f, acc10 = 0.f, acc11 = 0.f;
  for (int k0 = 0; k0 < K; k0 += 16){
#pragma unroll
    for (int i = 0; i < 2; ++i){
      int idx = t + i * 256;
      int r = idx >> 4, kk = idx & 15;
      int gr = m0 + r, gk = k0 + kk;
      float v;
      if (gk < split) v = A1[(size_t)gr * split + gk];
      else            v = ldin(A2, (size_t)gr * (K - split) + (gk - split), isbf);
      As[r][kk] = v;
    }
#pragma unroll
    for (int i = 0; i < 2; ++i){
      int idx = t + i * 256;
      if constexpr (BT){
        int o = idx >> 4, kk = idx & 15;
        Ws[kk][o] = ldin(W, woff + (size_t)(n0 + o) * K + (k0 + kk), isbf);
      } else {
        int kk = idx >> 5, o = idx & 31;
        Ws[kk][o] = ldin(W, woff + (size_t)(k0 + kk) * N + (n0 + o), isbf);
      }
    }
    __syncthreads();
#pragma unroll
    for (int kk = 0; kk < 16; ++kk){
      float a0 = As[ty*2 + 0][kk], a1 = As[ty*2 + 1][kk];
      float w0 = Ws[kk][tx*2 + 0], w1 = Ws[kk][tx*2 + 1];
      acc00 += a0 * w0; acc01 += a0 * w1;
      acc10 += a1 * w0; acc11 += a1 * w1;
    }
    __syncthreads();
  }
  int r0 = m0 + ty*2, c0 = n0 + tx*2;
  if constexpr (MUL){
    acc00 *= mulv[(size_t)r0*N + c0];       acc01 *= mulv[(size_t)r0*N + c0 + 1];
    acc10 *= mulv[(size_t)(r0+1)*N + c0];   acc11 *= mulv[(size_t)(r0+1)*N + c0 + 1];
  }
  C[(size_t)r0*N + c0]     = acc00; C[(size_t)r0*N + c0 + 1]     = acc01;
  C[(size_t)(r0+1)*N + c0] = acc10; C[(size_t)(r0+1)*N + c0 + 1] = acc11;
}

// ---- ghost-BN + GLU: H (1024x256) -> G (1024x128) --------------------------
__global__ __launch_bounds__(256)
void gbn_glu_k(const float* __restrict__ H, const void* __restrict__ w,
               const void* __restrict__ b, size_t off, float* __restrict__ G,
               const float* __restrict__ flg){
  __shared__ float sm[256], si[256], sw[256], sbv[256];
  const int isbf = flg[0] != 0.0f;
  int g = blockIdx.x, t = threadIdx.x;
  const float* Hg = H + (size_t)g * VBS * 256;
  float s = 0.f, ss = 0.f;
  for (int r = 0; r < VBS; ++r){ float v = Hg[r*256 + t]; s += v; ss += v*v; }
  float m  = s * (1.f / VBS);
  float is = rsqrtf(ss * (1.f / VBS) - m*m + BN_EPS_C);
  sm[t] = m; si[t] = is; sw[t] = ldin(w, off + t, isbf); sbv[t] = ldin(b, off + t, isbf);
  __syncthreads();
  float* Gg = G + (size_t)g * VBS * 128;
  for (int i = 0; i < 64; ++i){
    int idx = t + i * 256;          // 0..16383
    int r = idx >> 7, j = idx & 127;
    float h0 = Hg[r*256 + j];
    float h1 = Hg[r*256 + j + 128];
    h0 = (h0 - sm[j])     * si[j]     * sw[j]     + sbv[j];
    h1 = (h1 - sm[j+128]) * si[j+128] * sw[j+128] + sbv[j+128];
    Gg[r*128 + j] = h0 * (1.f / (1.f + __expf(-h1)));
  }
}

// ---- ghost-BN only: H (1024x256) -> O (1024x256) ---------------------------
__global__ __launch_bounds__(256)
void gbn_k(const float* __restrict__ H, const void* __restrict__ w,
           const void* __restrict__ b, size_t off, float* __restrict__ O,
           const float* __restrict__ flg){
  const int isbf = flg[0] != 0.0f;
  int g = blockIdx.x, t = threadIdx.x;
  const float* Hg = H + (size_t)g * VBS * 256;
  float s = 0.f, ss = 0.f;
  for (int r = 0; r < VBS; ++r){ float v = Hg[r*256 + t]; s += v; ss += v*v; }
  float m  = s * (1.f / VBS);
  float is = rsqrtf(ss * (1.f / VBS) - m*m + BN_EPS_C);
  float sw = ldin(w, off + t, isbf), sb = ldin(b, off + t, isbf);
  float* Og = O + (size_t)g * VBS * 256;
  for (int r = 0; r < VBS; ++r)
    Og[r*256 + t] = (Hg[r*256 + t] - m) * is * sw + sb;
}

// ---- sparsemax per row via bisection on tau --------------------------------
__global__ __launch_bounds__(256)
void sparsemax_k(const float* __restrict__ anorm, float* __restrict__ prior,
                 float* __restrict__ tab, float* __restrict__ lrow){
  __shared__ float sb[256];
  int brow = blockIdx.x, t = threadIdx.x;
  size_t idx = (size_t)brow * 256 + t;
  float pr = prior[idx];
  float z  = anorm[idx] * pr;
  float zmax = block_red<1>(z, sb);
  float lo = zmax - 1.f, hi = zmax;
#pragma unroll 1
  for (int it = 0; it < 40; ++it){
    float mid = 0.5f * (lo + hi);
    float d = z - mid;
    float ssum = block_red<0>(d > 0.f ? d : 0.f, sb);
    if (ssum >= 1.f) lo = mid; else hi = mid;
  }
  float tau = 0.5f * (lo + hi);
  float p = z - tau; p = p > 0.f ? p : 0.f;
  tab[idx]   = p;
  prior[idx] = pr * (GAMMA_C - p);
  float l = block_red<0>(p * __logf(p + 1e-15f), sb);
  if (t == 0) lrow[brow] = l;
}

// ---- 1D self-attention + f32 amap write ------------------------------------
__global__ __launch_bounds__(256)
void selfattn_k(const float* __restrict__ xm, float* __restrict__ y,
                const void* __restrict__ in_w, const void* __restrict__ in_b,
                const void* __restrict__ out_w, const void* __restrict__ out_b,
                int s, float* __restrict__ amap, const float* __restrict__ flg){
  __shared__ float qs[256], ks[256], vs[256], ms[256], rz[256], sb[256];
  const int isbf = flg[0] != 0.0f;
  int b = blockIdx.x, t = threadIdx.x;
  float w0 = ldin(in_w, s*3+0, isbf), w1 = ldin(in_w, s*3+1, isbf), w2 = ldin(in_w, s*3+2, isbf);
  float b0 = ldin(in_b, s*3+0, isbf), b1 = ldin(in_b, s*3+1, isbf), b2 = ldin(in_b, s*3+2, isbf);
  float ow = ldin(out_w, s, isbf), ob = ldin(out_b, s, isbf);
  float xv = xm[(size_t)b*256 + t];
  float q = xv*w0 + b0, k = xv*w1 + b1, v = xv*w2 + b2;
  qs[t] = q; ks[t] = k; vs[t] = v;
  float kmax = block_red<1>(k, sb);
  float kmin = block_red<2>(k, sb);
  // pass A: thread t owns output row i=t
  float mi = (q >= 0.f) ? q*kmax : q*kmin;
  float Z = 0.f, Y = 0.f;
#pragma unroll 4
  for (int j = 0; j < 256; ++j){
    float e = __expf(q*ks[j] - mi);
    Z += e; Y += e*vs[j];
  }
  float rZ = 1.f / Z;
  y[(size_t)b*256 + t] = Y*rZ*ow + ob;
  ms[t] = mi; rz[t] = rZ;
  __syncthreads();
  // pass B: write normalized attention rows, coalesced f32 stores
  float kt = ks[t];
  size_t base = ((size_t)s*BATCH + b) * 65536;
#pragma unroll 4
  for (int i = 0; i < 256; ++i){
    amap[base + (size_t)i*256 + t] = __expf(qs[i]*kt - ms[i]) * rz[i];
  }
}

// ---- combine: feat = (G0+G1)*sqrt(.5); split into steps/att ----------------
__global__ void combine_k(const float* __restrict__ G0, const float* __restrict__ G1,
                          float* __restrict__ att, float* __restrict__ steps_out){
  int idx = blockIdx.x * 256 + threadIdx.x;  // 0..131071
  int brow = idx >> 7, j = idx & 127;
  float f = (G0[idx] + G1[idx]) * SQRT_HALF_C;
  if (j < 64){
    if (steps_out){
      steps_out[(size_t)brow*64 + j] = f > 0.f ? f : 0.01f*f;
    }
  } else {
    att[(size_t)brow*64 + (j - 64)] = f;
  }
}

// ---- final m_loss ----------------------------------------------------------
__global__ void mloss_k(const float* __restrict__ lrow, float* __restrict__ outp){
  __shared__ float sb[256];
  int t = threadIdx.x;
  float s = 0.f;
  for (int i = t; i < N_STEPS*BATCH; i += 256) s += lrow[i];
  s = block_red<0>(s, sb);
  if (t == 0) outp[0] = s * (1.f/(N_STEPS*(float)BATCH));
}

extern "C" void kernel_launch(void* const* d_in, const int* in_sizes, int n_in,
                              void* d_out, int out_size, void* d_ws, size_t ws_size,
                              hipStream_t stream){
  const void* x         = d_in[0];
  const void* bemv      = d_in[1];
  const void* gmat      = d_in[2];
  const void* bn_w      = d_in[3];
  const void* bn_b      = d_in[4];
  const void* init_fc0  = d_in[5];
  const void* init_bnw0 = d_in[6];
  const void* init_bnb0 = d_in[7];
  const void* init_fc1  = d_in[8];
  const void* init_bnw1 = d_in[9];
  const void* init_bnb1 = d_in[10];
  const void* step_fc0  = d_in[11];
  const void* step_bnw0 = d_in[12];
  const void* step_bnb0 = d_in[13];
  const void* step_fc1  = d_in[14];
  const void* step_bnw1 = d_in[15];
  const void* step_bnb1 = d_in[16];
  const void* att_fc    = d_in[17];
  const void* att_bnw   = d_in[18];
  const void* att_bnb   = d_in[19];
  const void* sa_in_w   = d_in[20];
  const void* sa_in_b   = d_in[21];
  const void* sa_out_w  = d_in[22];
  const void* sa_out_b  = d_in[23];

  float* out       = (float*)d_out;
  float* steps_out = out;                                  // 3*1024*64 f32
  float* mloss_out = out + (size_t)N_STEPS*BATCH*N_D;      // 1 f32
  float* amaps     = mloss_out + 1;                        // 3*1024*256*256 f32

  float* w     = (float*)d_ws;
  float* mean  = w;                 // 256
  float* istd  = w + 256;           // 256
  float* lrow  = w + 512;           // 3072
  float* flag  = w + 3584;          // 1
  float* xn    = w + 4096;          // 262144
  float* H     = xn   + 262144;     // 262144
  float* G0    = H    + 262144;     // 131072
  float* G1    = G0   + 131072;     // 131072
  float* att   = G1   + 131072;     // 65536
  float* anorm = att  + 65536;      // 262144
  float* tab   = anorm + 262144;    // 262144
  float* prior = tab  + 262144;     // 262144
  float* xm    = prior + 262144;    // 262144
  float* y     = xm   + 262144;     // 262144

  dim3 gemmGrid(256/32, 1024/32);   // all GEMMs: M=1024, N=256

  detect_k<<<1, 256, 0, stream>>>((const unsigned short*)x, flag);
  init_k<<<1024, 256, 0, stream>>>(prior);
  bnstats_k<<<256, 256, 0, stream>>>(x, mean, istd, flag);
  xn_k<<<1024, 256, 0, stream>>>(x, mean, istd, bn_w, bn_b, xn, flag);

  // initial feature transformer on [xn | bemv]
  gemm_k<true,false><<<gemmGrid, 256, 0, stream>>>(xn, bemv, 256, init_fc0, 0, nullptr, H, 1024, 256, 512, flag);
  gbn_glu_k<<<8, 256, 0, stream>>>(H, init_bnw0, init_bnb0, 0, G0, flag);
  gemm_k<true,false><<<gemmGrid, 256, 0, stream>>>(G0, nullptr, 128, init_fc1, 0, nullptr, H, 1024, 256, 128, flag);
  gbn_glu_k<<<8, 256, 0, stream>>>(H, init_bnw1, init_bnb1, 0, G1, flag);
  combine_k<<<512, 256, 0, stream>>>(G0, G1, att, nullptr);

  for (int s = 0; s < N_STEPS; ++s){
    // a = GBN(att @ att_fc[s].T)
    gemm_k<true,false><<<gemmGrid, 256, 0, stream>>>(att, nullptr, 64, att_fc, (size_t)s*AD*N_A, nullptr, H, 1024, 256, 64, flag);
    gbn_k<<<8, 256, 0, stream>>>(H, att_bnw, att_bnb, (size_t)s*256, anorm, flag);
    // sparsemax + prior update + loss partials
    sparsemax_k<<<1024, 256, 0, stream>>>(anorm, prior, tab, lrow + s*1024);
    // x_masked = (tab @ gmat) * xn
    gemm_k<false,true><<<gemmGrid, 256, 0, stream>>>(tab, nullptr, 256, gmat, 0, xn, xm, 1024, 256, 256, flag);
    // self-attn + amap output
    selfattn_k<<<1024, 256, 0, stream>>>(xm, y, sa_in_w, sa_in_b, sa_out_w, sa_out_b, s, amaps, flag);
    // step feature transformer on [y | bemv]
    gemm_k<true,false><<<gemmGrid, 256, 0, stream>>>(y, bemv, 256, step_fc0, (size_t)s*256*512, nullptr, H, 1024, 256, 512, flag);
    gbn_glu_k<<<8, 256, 0, stream>>>(H, step_bnw0, step_bnb0, (size_t)s*256, G0, flag);
    gemm_k<true,false><<<gemmGrid, 256, 0, stream>>>(G0, nullptr, 128, step_fc1, (size_t)s*256*128, nullptr, H, 1024, 256, 128, flag);
    gbn_glu_k<<<8, 256, 0, stream>>>(H, step_bnw1, step_bnb1, (size_t)s*256, G1, flag);
    combine_k<<<512, 256, 0, stream>>>(G0, G1, att, steps_out + (size_t)s*BATCH*N_D);
  }
  mloss_k<<<1, 256, 0, stream>>>(lrow, mloss_out);
}

// Round 3
// 532.708 us; speedup vs baseline: 1.4010x; 1.4010x over previous
//
#include <hip/hip_runtime.h>
#include <hip/hip_bf16.h>

#define BATCH 1024
#define F_IN 256
#define N_D 64
#define N_A 64
#define VBS 128
#define N_STEPS 3
#define FO 128
#define D_CAT 512
#define AD 256
#define GAMMA_C 1.3f
#define BN_EPS_C 1e-5f
#define SQRT_HALF_C 0.70710678118654752440f

// ---- input loader: f32 or bf16 decided at runtime by detector flag --------
__device__ __forceinline__ float ldin(const void* p, size_t i, int isbf){
  if (isbf) return __bfloat162float(((const __hip_bfloat16*)p)[i]);
  return ((const float*)p)[i];
}
__device__ __forceinline__ float4 ld4(const void* p, size_t i, int isbf){
  if (!isbf) return *(const float4*)((const float*)p + i);
  const __hip_bfloat16* q = (const __hip_bfloat16*)p + i;
  return make_float4(__bfloat162float(q[0]), __bfloat162float(q[1]),
                     __bfloat162float(q[2]), __bfloat162float(q[3]));
}

// ---- wave (64-lane) butterfly reductions: result in ALL lanes -------------
__device__ __forceinline__ float wsum(float v){
#pragma unroll
  for (int o = 32; o > 0; o >>= 1) v += __shfl_xor(v, o);
  return v;
}
__device__ __forceinline__ float wmaxr(float v){
#pragma unroll
  for (int o = 32; o > 0; o >>= 1) v = fmaxf(v, __shfl_xor(v, o));
  return v;
}
__device__ __forceinline__ float wminr(float v){
#pragma unroll
  for (int o = 32; o > 0; o >>= 1) v = fminf(v, __shfl_xor(v, o));
  return v;
}
// ---- LDS tree block sum (256 threads) for the two once-per-call kernels ---
__device__ __forceinline__ float block_sum(float v, float* sb){
  int t = threadIdx.x;
  sb[t] = v; __syncthreads();
#pragma unroll
  for (int s = 128; s > 0; s >>= 1){
    if (t < s) sb[t] += sb[t + s];
    __syncthreads();
  }
  float r = sb[0]; __syncthreads();
  return r;
}

// ---- dtype detector (even uint16s: f32 mantissa=uniform, bf16=narrow exp) -
__global__ void detect_k(const unsigned short* __restrict__ u, float* __restrict__ flag){
  __shared__ int cnt;
  if (threadIdx.x == 0) cnt = 0;
  __syncthreads();
  int c = 0;
  for (int j = 0; j < 16; ++j){
    unsigned short v = u[(size_t)(threadIdx.x * 16 + j) * 2];
    int e = (v >> 7) & 0xFF;
    if (e >= 118 && e <= 134) c++;
  }
  atomicAdd(&cnt, c);
  __syncthreads();
  if (threadIdx.x == 0) flag[0] = (cnt > 2048) ? 1.0f : 0.0f;
}

// ---- full-batch BN stats (one block per feature) ---------------------------
__global__ void bnstats_k(const void* __restrict__ x, float* __restrict__ mean,
                          float* __restrict__ istd, const float* __restrict__ flg){
  __shared__ float sb[256];
  const int isbf = flg[0] != 0.0f;
  int f = blockIdx.x, t = threadIdx.x;
  float s = 0.f, ss = 0.f;
  for (int r = t; r < BATCH; r += 256){
    float v = ldin(x, (size_t)r * F_IN + f, isbf);
    s += v; ss += v * v;
  }
  s  = block_sum(s, sb);
  ss = block_sum(ss, sb);
  if (t == 0){
    float m = s * (1.f / BATCH);
    mean[f] = m;
    istd[f] = rsqrtf(ss * (1.f / BATCH) - m * m + BN_EPS_C);
  }
}

__global__ void xn_k(const void* __restrict__ x, const float* __restrict__ mean,
                     const float* __restrict__ istd, const void* __restrict__ bw,
                     const void* __restrict__ bb, float* __restrict__ xn,
                     const float* __restrict__ flg){
  const int isbf = flg[0] != 0.0f;
  int idx = blockIdx.x * 256 + threadIdx.x;
  int f = idx & (F_IN - 1);
  xn[idx] = (ldin(x, idx, isbf) - mean[f]) * istd[f] * ldin(bw, f, isbf) + ldin(bb, f, isbf);
}

// ---- GEMM (BT): C(1024x256) = A(1024xK) @ W^T, W (256,K) row-major --------
// A = virtual concat [A1 f32 | A2 input] split at `split` cols. BK=32,
// float4 loads, reg double-buffer, LDS [kk][r] so fragments are ds_read_b64.
__global__ __launch_bounds__(256)
void gemm_bt_k(const float* __restrict__ A1, const void* __restrict__ A2, int split,
               const void* __restrict__ W, size_t woff, float* __restrict__ C,
               int K, const float* __restrict__ flg){
  __shared__ float As[32][34];
  __shared__ float Ws[32][34];
  const int isbf = flg[0] != 0.0f;
  const int n0 = blockIdx.x * 32, m0 = blockIdx.y * 32;
  const int t = threadIdx.x;
  const int tx = t & 15, ty = t >> 4;
  const int lr = t >> 3, lk = (t & 7) * 4;
  const int nc = K >> 5;
  float a00 = 0.f, a01 = 0.f, a10 = 0.f, a11 = 0.f;

  auto lda = [&](int k0) -> float4 {
    int gk = k0 + lk, gr = m0 + lr;
    if (gk < split) return *(const float4*)(A1 + (size_t)gr * split + gk);
    return ld4(A2, (size_t)gr * (K - split) + (gk - split), isbf);
  };
  auto ldw = [&](int k0) -> float4 {
    return ld4(W, woff + (size_t)(n0 + lr) * K + k0 + lk, isbf);
  };

  float4 ra = lda(0), rw = ldw(0);
  for (int c = 0; c < nc; ++c){
    As[lk+0][lr] = ra.x; As[lk+1][lr] = ra.y; As[lk+2][lr] = ra.z; As[lk+3][lr] = ra.w;
    Ws[lk+0][lr] = rw.x; Ws[lk+1][lr] = rw.y; Ws[lk+2][lr] = rw.z; Ws[lk+3][lr] = rw.w;
    __syncthreads();
    float4 na = ra, nw = rw;
    if (c + 1 < nc){ na = lda((c+1) << 5); nw = ldw((c+1) << 5); }
#pragma unroll
    for (int kk = 0; kk < 32; ++kk){
      float2 av = *(const float2*)&As[kk][ty*2];
      float2 wv = *(const float2*)&Ws[kk][tx*2];
      a00 += av.x * wv.x; a01 += av.x * wv.y;
      a10 += av.y * wv.x; a11 += av.y * wv.y;
    }
    __syncthreads();
    ra = na; rw = nw;
  }
  int r0 = m0 + ty*2, c0 = n0 + tx*2;
  float* Cp = C + (size_t)r0 * 256 + c0;
  Cp[0] = a00; Cp[1] = a01; Cp[256] = a10; Cp[257] = a11;
}

// ---- ghost-BN stats -> per-(group,col) affine (a = istd*w, b2 = b - m*a) --
// grid (8 colchunks, 8 groups), 256 thr = 32 cols x 8 row-octiles
__global__ __launch_bounds__(256)
void gstats_k(const float* __restrict__ H, const void* __restrict__ w,
              const void* __restrict__ b, size_t off, float* __restrict__ sa,
              float* __restrict__ sb, const float* __restrict__ flg){
  __shared__ float ps[8][32], pss[8][32];
  const int isbf = flg[0] != 0.0f;
  int c0 = blockIdx.x * 32, g = blockIdx.y;
  int tx = threadIdx.x & 31, q = threadIdx.x >> 5;
  const float* Hp = H + ((size_t)g*128 + q*16) * 256 + c0 + tx;
  float s = 0.f, ss = 0.f;
#pragma unroll
  for (int i = 0; i < 16; ++i){ float v = Hp[(size_t)i*256]; s += v; ss += v*v; }
  ps[q][tx] = s; pss[q][tx] = ss;
  __syncthreads();
  if (threadIdx.x < 32){
    int t = threadIdx.x, col = c0 + t;
    float S = 0.f, SS = 0.f;
#pragma unroll
    for (int qq = 0; qq < 8; ++qq){ S += ps[qq][t]; SS += pss[qq][t]; }
    float m = S * (1.f/128), is = rsqrtf(SS * (1.f/128) - m*m + BN_EPS_C);
    float wv = ldin(w, off + col, isbf), bv = ldin(b, off + col, isbf);
    float A = is * wv;
    sa[g*256 + col] = A;
    sb[g*256 + col] = bv - m * A;
  }
}

// ---- sparsemax: wave-per-row, zero barriers. Fuses GBN-normalize, prior ---
__global__ __launch_bounds__(256)
void spmax_k(const float* __restrict__ H, const float* __restrict__ sa,
             const float* __restrict__ sb, float* __restrict__ prior,
             float* __restrict__ tab, float* __restrict__ lrow, int first){
  int lane = threadIdx.x & 63, wv = threadIdx.x >> 6;
  int b = blockIdx.x * 4 + wv, g = b >> 7;
  size_t rb = (size_t)b * 256;
  float z[4], pr[4];
#pragma unroll
  for (int e = 0; e < 4; ++e){
    int j = e*64 + lane;
    pr[e] = first ? 1.f : prior[rb + j];
    z[e] = (H[rb + j] * sa[g*256 + j] + sb[g*256 + j]) * pr[e];
  }
  float zm = wmaxr(fmaxf(fmaxf(z[0], z[1]), fmaxf(z[2], z[3])));
  float lo = zm - 1.f, hi = zm;
#pragma unroll 1
  for (int it = 0; it < 30; ++it){
    float mid = 0.5f * (lo + hi);
    float s = 0.f;
#pragma unroll
    for (int e = 0; e < 4; ++e){ float d = z[e] - mid; s += d > 0.f ? d : 0.f; }
    s = wsum(s);
    if (s >= 1.f) lo = mid; else hi = mid;
  }
  float tau = 0.5f * (lo + hi);
  float ls = 0.f;
#pragma unroll
  for (int e = 0; e < 4; ++e){
    int j = e*64 + lane;
    float p = z[e] - tau; p = p > 0.f ? p : 0.f;
    tab[rb + j]   = p;
    prior[rb + j] = pr[e] * (GAMMA_C - p);
    ls += p * __logf(p + 1e-15f);
  }
  ls = wsum(ls);
  if (lane == 0) lrow[b] = ls;
}

// ---- fused x_masked GEMM + 1D self-attention + amap write -----------------
__global__ __launch_bounds__(256)
void attn_k(const float* __restrict__ tab, const void* __restrict__ gmat,
            const float* __restrict__ xn, float* __restrict__ y,
            const void* __restrict__ in_w, const void* __restrict__ in_b,
            const void* __restrict__ out_w, const void* __restrict__ out_b,
            int s, float* __restrict__ amap, const float* __restrict__ flg){
  __shared__ __align__(16) float tabs[256], qs[256], ks[256], vs[256], ms[256], rz[256];
  __shared__ float r1[4], r2[4];
  const int isbf = flg[0] != 0.0f;
  int b = blockIdx.x, t = threadIdx.x;
  tabs[t] = tab[(size_t)b*256 + t];
  __syncthreads();
  // xm[t] = sum_k tab[b][k] * gmat[k][t]  (gmat 256KB, L2-resident)
  float xm = 0.f;
  if (isbf){
    const __hip_bfloat16* gm = (const __hip_bfloat16*)gmat;
#pragma unroll 8
    for (int k2 = 0; k2 < 256; ++k2) xm += tabs[k2] * __bfloat162float(gm[k2*256 + t]);
  } else {
    const float* gm = (const float*)gmat;
#pragma unroll 8
    for (int k2 = 0; k2 < 256; ++k2) xm += tabs[k2] * gm[k2*256 + t];
  }
  xm *= xn[(size_t)b*256 + t];
  float w0 = ldin(in_w, s*3+0, isbf), w1 = ldin(in_w, s*3+1, isbf), w2 = ldin(in_w, s*3+2, isbf);
  float b0 = ldin(in_b, s*3+0, isbf), b1 = ldin(in_b, s*3+1, isbf), b2 = ldin(in_b, s*3+2, isbf);
  float ow = ldin(out_w, s, isbf), ob = ldin(out_b, s, isbf);
  float q = xm*w0 + b0, k = xm*w1 + b1, v = xm*w2 + b2;
  qs[t] = q; ks[t] = k; vs[t] = v;
  int lane = t & 63, wv = t >> 6;
  float km = wmaxr(k), kn = wminr(k);
  if (lane == 0){ r1[wv] = km; r2[wv] = kn; }
  __syncthreads();
  float kmax = fmaxf(fmaxf(r1[0], r1[1]), fmaxf(r1[2], r1[3]));
  float kmin = fminf(fminf(r2[0], r2[1]), fminf(r2[2], r2[3]));
  // pass A: thread t owns row i=t; closed-form row max
  float mi = (q >= 0.f) ? q*kmax : q*kmin;
  float Z = 0.f, Y = 0.f;
#pragma unroll 8
  for (int j = 0; j < 256; j += 4){
    float4 k4 = *(const float4*)&ks[j];
    float4 v4 = *(const float4*)&vs[j];
    float e0 = __expf(q*k4.x - mi), e1 = __expf(q*k4.y - mi);
    float e2 = __expf(q*k4.z - mi), e3 = __expf(q*k4.w - mi);
    Z += (e0 + e1) + (e2 + e3);
    Y += (e0*v4.x + e1*v4.y) + (e2*v4.z + e3*v4.w);
  }
  float rzv = 1.f / Z;
  y[(size_t)b*256 + t] = Y*rzv*ow + ob;
  ms[t] = mi; rz[t] = rzv;
  __syncthreads();
  // pass B: thread t = column t, coalesced b32 nontemporal stores
  float kt = ks[t];
  size_t base = ((size_t)s*BATCH + b) * 65536 + t;
#pragma unroll 4
  for (int i0 = 0; i0 < 256; i0 += 4){
    float4 q4 = *(const float4*)&qs[i0];
    float4 m4 = *(const float4*)&ms[i0];
    float4 s4 = *(const float4*)&rz[i0];
    __builtin_nontemporal_store(__expf(q4.x*kt - m4.x) * s4.x, amap + base + (size_t)(i0+0)*256);
    __builtin_nontemporal_store(__expf(q4.y*kt - m4.y) * s4.y, amap + base + (size_t)(i0+1)*256);
    __builtin_nontemporal_store(__expf(q4.z*kt - m4.z) * s4.z, amap + base + (size_t)(i0+2)*256);
    __builtin_nontemporal_store(__expf(q4.w*kt - m4.w) * s4.w, amap + base + (size_t)(i0+3)*256);
  }
}

// ---- ghost-BN + GLU (+ optional combine epilogue) -------------------------
// grid (4 colchunks, 8 groups), 256 thr. MODE 0: write G0. MODE 1: combine
// f=(G0+glu)*sqrt_half -> steps_out (j<64, leaky) / att (j>=64).
template<int MODE>
__global__ __launch_bounds__(256)
void gbnglu_k(const float* __restrict__ H, const void* __restrict__ w,
              const void* __restrict__ b, size_t off, const float* __restrict__ G0,
              float* __restrict__ Gout, float* __restrict__ att,
              float* __restrict__ steps_out, const float* __restrict__ flg){
  __shared__ float ps[4][64], pss[4][64];
  __shared__ float sA[64], sB[64];
  const int isbf = flg[0] != 0.0f;
  int c0 = blockIdx.x * 32, g = blockIdx.y;
  int t = threadIdx.x;
  int tx = t & 63, q = t >> 6;
  int cc = tx & 31, half = tx >> 5;
  int col = c0 + cc + half*128;
  const float* Hp = H + ((size_t)g*128 + q*32) * 256 + col;
  float s = 0.f, ss = 0.f;
#pragma unroll
  for (int i = 0; i < 32; ++i){ float v = Hp[(size_t)i*256]; s += v; ss += v*v; }
  ps[q][tx] = s; pss[q][tx] = ss;
  __syncthreads();
  if (t < 64){
    float S  = ps[0][t] + ps[1][t] + ps[2][t] + ps[3][t];
    float SS = pss[0][t] + pss[1][t] + pss[2][t] + pss[3][t];
    float m  = S * (1.f/128), is = rsqrtf(SS * (1.f/128) - m*m + BN_EPS_C);
    int colT = c0 + (t & 31) + (t >> 5)*128;
    float wv = ldin(w, off + colT, isbf), bv = ldin(b, off + colT, isbf);
    float A = is * wv;
    sA[t] = A; sB[t] = bv - m*A;
  }
  __syncthreads();
  int oc = t & 31;
  int rbase = (t >> 5) * 16;
#pragma unroll
  for (int i = 0; i < 16; ++i){
    int r = g*128 + rbase + i;
    float h0 = H[(size_t)r*256 + c0 + oc];
    float h1 = H[(size_t)r*256 + c0 + oc + 128];
    float n0 = h0 * sA[oc]    + sB[oc];
    float n1 = h1 * sA[32+oc] + sB[32+oc];
    float gl = n0 / (1.f + __expf(-n1));
    int j = c0 + oc;
    if constexpr (MODE == 0){
      Gout[(size_t)r*128 + j] = gl;
    } else {
      float f = (G0[(size_t)r*128 + j] + gl) * SQRT_HALF_C;
      if (j < 64){
        if (steps_out) steps_out[(size_t)r*64 + j] = f > 0.f ? f : 0.01f*f;
      } else {
        att[(size_t)r*64 + (j - 64)] = f;
      }
    }
  }
}

// ---- final m_loss ----------------------------------------------------------
__global__ void mloss_k(const float* __restrict__ lrow, float* __restrict__ outp){
  __shared__ float sb[256];
  int t = threadIdx.x;
  float s = 0.f;
  for (int i = t; i < N_STEPS*BATCH; i += 256) s += lrow[i];
  s = block_sum(s, sb);
  if (t == 0) outp[0] = s * (1.f/(N_STEPS*(float)BATCH));
}

extern "C" void kernel_launch(void* const* d_in, const int* in_sizes, int n_in,
                              void* d_out, int out_size, void* d_ws, size_t ws_size,
                              hipStream_t stream){
  const void* x         = d_in[0];
  const void* bemv      = d_in[1];
  const void* gmat      = d_in[2];
  const void* bn_w      = d_in[3];
  const void* bn_b      = d_in[4];
  const void* init_fc0  = d_in[5];
  const void* init_bnw0 = d_in[6];
  const void* init_bnb0 = d_in[7];
  const void* init_fc1  = d_in[8];
  const void* init_bnw1 = d_in[9];
  const void* init_bnb1 = d_in[10];
  const void* step_fc0  = d_in[11];
  const void* step_bnw0 = d_in[12];
  const void* step_bnb0 = d_in[13];
  const void* step_fc1  = d_in[14];
  const void* step_bnw1 = d_in[15];
  const void* step_bnb1 = d_in[16];
  const void* att_fc    = d_in[17];
  const void* att_bnw   = d_in[18];
  const void* att_bnb   = d_in[19];
  const void* sa_in_w   = d_in[20];
  const void* sa_in_b   = d_in[21];
  const void* sa_out_w  = d_in[22];
  const void* sa_out_b  = d_in[23];

  float* out       = (float*)d_out;
  float* steps_out = out;                                  // 3*1024*64 f32
  float* mloss_out = out + (size_t)N_STEPS*BATCH*N_D;      // 1 f32
  float* amaps     = mloss_out + 1;                        // 3*1024*256*256 f32

  float* w     = (float*)d_ws;
  float* mean  = w;                  // 256
  float* istd  = w + 256;            // 256
  float* flag  = w + 512;            // 1 (+pad)
  float* lrow  = w + 1024;           // 3072
  float* sa    = w + 4096;           // 2048
  float* sbuf  = sa + 2048;          // 2048
  float* xn    = sbuf + 2048;        // 262144
  float* H     = xn   + 262144;      // 262144
  float* G0    = H    + 262144;      // 131072
  float* att   = G0   + 131072;      // 65536
  float* tab   = att  + 65536;       // 262144
  float* prior = tab  + 262144;      // 262144
  float* y     = prior + 262144;     // 262144

  dim3 gemmGrid(8, 32);
  dim3 gluGrid(4, 8);
  dim3 gstGrid(8, 8);

  detect_k<<<1, 256, 0, stream>>>((const unsigned short*)x, flag);
  bnstats_k<<<256, 256, 0, stream>>>(x, mean, istd, flag);
  xn_k<<<1024, 256, 0, stream>>>(x, mean, istd, bn_w, bn_b, xn, flag);

  // initial feature transformer on [xn | bemv]
  gemm_bt_k<<<gemmGrid, 256, 0, stream>>>(xn, bemv, 256, init_fc0, 0, H, 512, flag);
  gbnglu_k<0><<<gluGrid, 256, 0, stream>>>(H, init_bnw0, init_bnb0, 0, nullptr, G0, nullptr, nullptr, flag);
  gemm_bt_k<<<gemmGrid, 256, 0, stream>>>(G0, nullptr, 128, init_fc1, 0, H, 128, flag);
  gbnglu_k<1><<<gluGrid, 256, 0, stream>>>(H, init_bnw1, init_bnb1, 0, G0, nullptr, att, nullptr, flag);

  for (int s = 0; s < N_STEPS; ++s){
    // a = GBN(att @ att_fc[s]^T)
    gemm_bt_k<<<gemmGrid, 256, 0, stream>>>(att, nullptr, 64, att_fc, (size_t)s*AD*N_A, H, 64, flag);
    gstats_k<<<gstGrid, 256, 0, stream>>>(H, att_bnw, att_bnb, (size_t)s*256, sa, sbuf, flag);
    // sparsemax (wave-per-row) + prior + loss partials
    spmax_k<<<256, 256, 0, stream>>>(H, sa, sbuf, prior, tab, lrow + s*1024, s == 0);
    // fused x_masked + self-attn + amap
    attn_k<<<1024, 256, 0, stream>>>(tab, gmat, xn, y, sa_in_w, sa_in_b, sa_out_w, sa_out_b, s, amaps, flag);
    // step feature transformer on [y | bemv]
    gemm_bt_k<<<gemmGrid, 256, 0, stream>>>(y, bemv, 256, step_fc0, (size_t)s*256*512, H, 512, flag);
    gbnglu_k<0><<<gluGrid, 256, 0, stream>>>(H, step_bnw0, step_bnb0, (size_t)s*256, nullptr, G0, nullptr, nullptr, flag);
    gemm_bt_k<<<gemmGrid, 256, 0, stream>>>(G0, nullptr, 128, step_fc1, (size_t)s*256*128, H, 128, flag);
    gbnglu_k<1><<<gluGrid, 256, 0, stream>>>(H, step_bnw1, step_bnb1, (size_t)s*256, G0, nullptr, att,
                                             steps_out + (size_t)s*BATCH*N_D, flag);
  }
  mloss_k<<<1, 256, 0, stream>>>(lrow, mloss_out);
}